// Round 1
// baseline (181.581 us; speedup 1.0000x reference)
//
#include <hip/hip_runtime.h>
#include <math.h>

#define BB 4
#define NN 512
#define LL 512
#define HH 8
#define DD 64
#define EE 25
#define KK 32
#define LOUT 416
#define EPSF 1e-6f

// ws layout (floats):
//  [0,        131072)  embedBuf  (2048 x 64)
//  [131072,   131328)  sumEmbed  (4 x 64)
//  [131328,   196864)  vxn       (2048 x 32)
//  [196864,   262400)  vhn       (2048 x 32)
//  [262400,   275200)  Ct        (200 x 64)   conv_w transposed

// ---------------- K0: transpose conv_w (D,H,E) -> ((h,e), d) for coalesced reads
__global__ void k_transpose_cw(const float* __restrict__ cw, float* __restrict__ Ct) {
    int i = blockIdx.x * 256 + threadIdx.x;
    if (i < DD * HH * EE) {
        int d = i / (HH * EE);
        int he = i % (HH * EE);
        Ct[he * DD + d] = cw[i];
    }
}

// ---------------- K1: fused dilated-conv + proj + GELU -> embed (2048 x 64)
// One wave per bn row. lane = 8q + h; lane reads x flat[64j + lane] (coalesced).
// S[h][e] = sum_t pw[t] * x[t+4e, h] computed with a sliding register window of
// zero-padded proj_w; then embed_pre[d] = sum_{h,e} conv_w[d,h,e] * S[h,e].
__global__ __launch_bounds__(256) void k_embed(
    const float* __restrict__ x, const float* __restrict__ pw,
    const float* __restrict__ pb, const float* __restrict__ Ct,
    float* __restrict__ embedBuf, float* __restrict__ sumEmbed) {
    __shared__ float P[608];         // P[96+t] = pw[t], zero outside [0,416)
    __shared__ float Sl[4][8][EE];   // per-wave S[h][e]
    int tid = threadIdx.x;
    for (int i = tid; i < 608; i += 256) {
        int t = i - 96;
        P[i] = (t >= 0 && t < LOUT) ? pw[t] : 0.f;
    }
    __syncthreads();

    int w = tid >> 6, lane = tid & 63;
    int bn = blockIdx.x * 4 + w;
    const float* xp = x + (size_t)bn * (LL * HH);
    int h = lane & 7, q = lane >> 3;

    float W[25];
#pragma unroll
    for (int k = 0; k < 25; ++k) W[k] = P[q + 4 * k];   // W[k] = P[l + 4k], l=q
    float S[25];
#pragma unroll
    for (int e = 0; e < 25; ++e) S[e] = 0.f;

#pragma unroll
    for (int j = 0; j < 64; ++j) {
        float v = xp[64 * j + lane];           // x[l = q+8j, h]
#pragma unroll
        for (int k = 0; k < 25; ++k)           // S[e] += v * P[l + 4(24-e)]
            S[24 - k] = fmaf(v, W[k], S[24 - k]);
        if (j < 63) {                          // slide window by 8 (= 2 slots)
#pragma unroll
            for (int k = 0; k < 23; ++k) W[k] = W[k + 2];
            int l = q + 8 * j;
            W[23] = P[l + 100];
            W[24] = P[l + 104];
        }
    }
    // reduce over q (lanes 8 apart share h)
#pragma unroll
    for (int e = 0; e < 25; ++e) {
        S[e] += __shfl_xor(S[e], 8);
        S[e] += __shfl_xor(S[e], 16);
        S[e] += __shfl_xor(S[e], 32);
    }
    if (lane < 8) {
#pragma unroll
        for (int e = 0; e < 25; ++e) Sl[w][lane][e] = S[e];
    }
    __syncthreads();

    // stage 2: embed_pre[d] = sum_i Ct[i][d] * S[i], i = h*25+e
    float acc = pb[0];
    const float* sw = &Sl[w][0][0];
#pragma unroll 8
    for (int i = 0; i < 200; ++i)
        acc = fmaf(Ct[i * 64 + lane], sw[i], acc);
    float g = 0.5f * acc * (1.f + erff(acc * 0.70710678118654752f));
    embedBuf[(size_t)bn * 64 + lane] = g;
    atomicAdd(&sumEmbed[(bn >> 9) * 64 + lane], g);
}

// ---------------- K2: centered target rows -> normalized vx, vh (K=32 each)
// Block = 4 rows (same b). Wave w handles l-chunk w; lane<32 -> W0 col, else U0.
__global__ __launch_bounds__(256) void k_corr(
    const float* __restrict__ target, const float* __restrict__ W0,
    const float* __restrict__ U0, float* __restrict__ vxn, float* __restrict__ vhn) {
    __shared__ float T[4][512];
    __shared__ float mus[4];
    __shared__ float S2[4][4][64];
    int tid = threadIdx.x;
    int w = tid >> 6, lane = tid & 63;
    int r0 = blockIdx.x * 4;

    const float4* tp = (const float4*)(target + (size_t)r0 * 512);
    float4* tl = (float4*)&T[0][0];
    tl[tid] = tp[tid];
    tl[tid + 256] = tp[tid + 256];
    __syncthreads();

    float s = 0.f;
#pragma unroll
    for (int c = 0; c < 8; ++c) s += T[w][lane + 64 * c];
#pragma unroll
    for (int off = 1; off < 64; off <<= 1) s += __shfl_xor(s, off);
    if (lane == 0) mus[w] = s * (1.f / 512.f);
    __syncthreads();
#pragma unroll
    for (int c = 0; c < 8; ++c) {
        int i = tid + c * 256;
        T[i >> 9][i & 511] -= mus[i >> 9];
    }
    __syncthreads();

    const float* base = (lane < 32) ? W0 : U0;
    int k = lane & 31;
    float acc[4] = {0.f, 0.f, 0.f, 0.f};
    int l0 = w * 128;
#pragma unroll 4
    for (int li = 0; li < 128; ++li) {
        int l = l0 + li;
        float wv = base[l * 32 + k];
#pragma unroll
        for (int r = 0; r < 4; ++r) acc[r] = fmaf(wv, T[r][l], acc[r]);
    }
#pragma unroll
    for (int r = 0; r < 4; ++r) S2[w][r][lane] = acc[r];
    __syncthreads();

    int r = w;
    float tot = S2[0][r][lane] + S2[1][r][lane] + S2[2][r][lane] + S2[3][r][lane];
    float sq = tot * tot;
#pragma unroll
    for (int off = 1; off < 32; off <<= 1) sq += __shfl_xor(sq, off);
    float nrm = sqrtf(sq + EPSF);
    float o = tot / nrm;
    int row = r0 + r;
    if (lane < 32) vxn[(size_t)row * 32 + lane] = o;
    else           vhn[(size_t)row * 32 + (lane - 32)] = o;
}

// ---------------- K3: pearson + top-32 + sparse softmax + gated mix + attn mean
// Block = one n; wave = one b. p-row (512) lives in 8 regs/lane.
__global__ __launch_bounds__(256) void k_attn(
    const float* __restrict__ vxn, const float* __restrict__ vhn,
    const float* __restrict__ embedBuf, const float* __restrict__ sumEmbed,
    float* __restrict__ outO, float* __restrict__ outA) {
    __shared__ float plds[4][512];
    int tid = threadIdx.x;
    int b = tid >> 6, lane = tid & 63;
    int n = blockIdx.x;

    const float* vxp = vxn + ((size_t)(b * 512 + n)) * 32;
    float xk[32];
#pragma unroll
    for (int k2 = 0; k2 < 32; ++k2) xk[k2] = vxp[k2];   // wave-uniform -> s_loads

    float p[8];
#pragma unroll
    for (int jj = 0; jj < 8; ++jj) {
        int m = jj * 64 + lane;
        const float4* vp = (const float4*)(vhn + ((size_t)(b * 512 + m)) * 32);
        float acc = 0.f;
#pragma unroll
        for (int c = 0; c < 8; ++c) {
            float4 v4 = vp[c];
            acc = fmaf(xk[c * 4 + 0], v4.x, acc);
            acc = fmaf(xk[c * 4 + 1], v4.y, acc);
            acc = fmaf(xk[c * 4 + 2], v4.z, acc);
            acc = fmaf(xk[c * 4 + 3], v4.w, acc);
        }
        p[jj] = acc;
        plds[b][m] = acc;
    }
    __syncthreads();

    // attn = mean over b
#pragma unroll
    for (int c = 0; c < 2; ++c) {
        int m = tid + c * 256;
        outA[(size_t)n * 512 + m] =
            0.25f * (plds[0][m] + plds[1][m] + plds[2][m] + plds[3][m]);
    }

    // iterative top-32 with fused softmax/out accumulation
    float M = 0.f, expnegM = 1.f, expsum = 0.f, oacc = 0.f;
    const float* eb = embedBuf + (size_t)b * 512 * 64;
#pragma unroll 1
    for (int it = 0; it < 32; ++it) {
        float v = p[0];
        int mi = lane;
#pragma unroll
        for (int j = 1; j < 8; ++j) {
            if (p[j] > v) { v = p[j]; mi = j * 64 + lane; }
        }
#pragma unroll
        for (int off = 1; off < 64; off <<= 1) {
            float ov = __shfl_xor(v, off);
            int om = __shfl_xor(mi, off);
            if (ov > v || (ov == v && om < mi)) { v = ov; mi = om; }
        }
        if (it == 0) {
            M = fmaxf(v, 0.f);
            expnegM = __expf(-M);
            expsum = (float)(NN - KK) * expnegM;   // 480 zeros contribute e^{-M}
        }
        float wv = __expf(v - M);
        expsum += wv;
        oacc = fmaf(wv - expnegM, eb[(size_t)mi * 64 + lane], oacc);
#pragma unroll
        for (int j = 0; j < 8; ++j)
            if (mi == j * 64 + lane) p[j] = -INFINITY;
    }
    oacc = fmaf(expnegM, sumEmbed[b * 64 + lane], oacc);
    oacc /= expsum;
    outO[((size_t)(b * 512 + n)) * 64 + lane] = oacc;
}

extern "C" void kernel_launch(void* const* d_in, const int* in_sizes, int n_in,
                              void* d_out, int out_size, void* d_ws, size_t ws_size,
                              hipStream_t stream) {
    const float* x      = (const float*)d_in[0];
    const float* target = (const float*)d_in[1];
    const float* cw     = (const float*)d_in[2];
    const float* pw     = (const float*)d_in[3];
    const float* pb     = (const float*)d_in[4];
    const float* W0     = (const float*)d_in[5];
    const float* U0     = (const float*)d_in[6];

    float* out  = (float*)d_out;                 // (4,512,64)
    float* attn = out + 4 * 512 * 64;            // (512,512)

    float* ws       = (float*)d_ws;
    float* embedBuf = ws;                        // 131072
    float* sumEmbed = ws + 131072;               // 256
    float* vxn      = ws + 131328;               // 65536
    float* vhn      = ws + 196864;               // 65536
    float* Ct       = ws + 262400;               // 12800

    hipMemsetAsync(sumEmbed, 0, 256 * sizeof(float), stream);
    k_transpose_cw<<<50, 256, 0, stream>>>(cw, Ct);
    k_embed<<<512, 256, 0, stream>>>(x, pw, pb, Ct, embedBuf, sumEmbed);
    k_corr<<<512, 256, 0, stream>>>(target, W0, U0, vxn, vhn);
    k_attn<<<512, 256, 0, stream>>>(vxn, vhn, embedBuf, sumEmbed, out, attn);
}

// Round 2
// 181.249 us; speedup vs baseline: 1.0018x; 1.0018x over previous
//
#include <hip/hip_runtime.h>
#include <math.h>

#define BB 4
#define NN 512
#define LL 512
#define HH 8
#define DD 64
#define EE 25
#define KK 32
#define LOUT 416
#define EPSF 1e-6f

// ws layout (floats):
//  [0,        131072)  embedBuf  (2048 x 64)
//  [131072,   131328)  sumEmbed  (4 x 64)
//  [131328,   196864)  vxn       (2048 x 32)
//  [196864,   262400)  vhn       (2048 x 32)
//  [262400,   275200)  Ct        (200 x 64)   conv_w transposed

// ---------------- K0: transpose conv_w (D,H,E) -> ((h,e), d) for coalesced reads
__global__ void k_transpose_cw(const float* __restrict__ cw, float* __restrict__ Ct) {
    int i = blockIdx.x * 256 + threadIdx.x;
    if (i < DD * HH * EE) {
        int d = i / (HH * EE);
        int he = i % (HH * EE);
        Ct[he * DD + d] = cw[i];
    }
}

// ---------------- K1: fused dilated-conv + proj + GELU -> embed (2048 x 64)
__global__ __launch_bounds__(256) void k_embed(
    const float* __restrict__ x, const float* __restrict__ pw,
    const float* __restrict__ pb, const float* __restrict__ Ct,
    float* __restrict__ embedBuf) {
    __shared__ float P[608];         // P[96+t] = pw[t], zero outside [0,416)
    __shared__ float Sl[4][8][EE];   // per-wave S[h][e]
    int tid = threadIdx.x;
    for (int i = tid; i < 608; i += 256) {
        int t = i - 96;
        P[i] = (t >= 0 && t < LOUT) ? pw[t] : 0.f;
    }
    __syncthreads();

    int w = tid >> 6, lane = tid & 63;
    int bn = blockIdx.x * 4 + w;
    const float* xp = x + (size_t)bn * (LL * HH);
    int h = lane & 7, q = lane >> 3;

    float W[25];
#pragma unroll
    for (int k = 0; k < 25; ++k) W[k] = P[q + 4 * k];
    float S[25];
#pragma unroll
    for (int e = 0; e < 25; ++e) S[e] = 0.f;

#pragma unroll
    for (int j = 0; j < 64; ++j) {
        float v = xp[64 * j + lane];           // x[l = q+8j, h]
#pragma unroll
        for (int k = 0; k < 25; ++k)
            S[24 - k] = fmaf(v, W[k], S[24 - k]);
        if (j < 63) {                          // slide window by 8 (= 2 slots)
#pragma unroll
            for (int k = 0; k < 23; ++k) W[k] = W[k + 2];
            int l = q + 8 * j;
            W[23] = P[l + 100];
            W[24] = P[l + 104];
        }
    }
#pragma unroll
    for (int e = 0; e < 25; ++e) {
        S[e] += __shfl_xor(S[e], 8);
        S[e] += __shfl_xor(S[e], 16);
        S[e] += __shfl_xor(S[e], 32);
    }
    if (lane < 8) {
#pragma unroll
        for (int e = 0; e < 25; ++e) Sl[w][lane][e] = S[e];
    }
    __syncthreads();

    float acc = pb[0];
    const float* sw = &Sl[w][0][0];
#pragma unroll 8
    for (int i = 0; i < 200; ++i)
        acc = fmaf(Ct[i * 64 + lane], sw[i], acc);
    float g = 0.5f * acc * (1.f + erff(acc * 0.70710678118654752f));
    embedBuf[(size_t)bn * 64 + lane] = g;
}

// ---------------- K1b: sumEmbed[b][d] = sum_n embed[b,n,d] (replaces atomics)
__global__ __launch_bounds__(256) void k_sumembed(
    const float* __restrict__ embedBuf, float* __restrict__ sumEmbed) {
    int b = blockIdx.x, tid = threadIdx.x;
    int d = tid & 63, c = tid >> 6;
    float s = 0.f;
    for (int r = c; r < 512; r += 4)
        s += embedBuf[((size_t)b * 512 + r) * 64 + d];
    __shared__ float red[4][64];
    red[c][d] = s;
    __syncthreads();
    if (c == 0)
        sumEmbed[b * 64 + d] = red[0][d] + red[1][d] + red[2][d] + red[3][d];
}

// ---------------- K2: centered target rows -> normalized vx, vh (K=32 each)
__global__ __launch_bounds__(256) void k_corr(
    const float* __restrict__ target, const float* __restrict__ W0,
    const float* __restrict__ U0, float* __restrict__ vxn, float* __restrict__ vhn) {
    __shared__ float T[4][512];
    __shared__ float mus[4];
    __shared__ float S2[4][4][64];
    int tid = threadIdx.x;
    int w = tid >> 6, lane = tid & 63;
    int r0 = blockIdx.x * 4;

    const float4* tp = (const float4*)(target + (size_t)r0 * 512);
    float4* tl = (float4*)&T[0][0];
    tl[tid] = tp[tid];
    tl[tid + 256] = tp[tid + 256];
    __syncthreads();

    float s = 0.f;
#pragma unroll
    for (int c = 0; c < 8; ++c) s += T[w][lane + 64 * c];
#pragma unroll
    for (int off = 1; off < 64; off <<= 1) s += __shfl_xor(s, off);
    if (lane == 0) mus[w] = s * (1.f / 512.f);
    __syncthreads();
#pragma unroll
    for (int c = 0; c < 8; ++c) {
        int i = tid + c * 256;
        T[i >> 9][i & 511] -= mus[i >> 9];
    }
    __syncthreads();

    const float* base = (lane < 32) ? W0 : U0;
    int k = lane & 31;
    float acc[4] = {0.f, 0.f, 0.f, 0.f};
    int l0 = w * 128;
#pragma unroll 4
    for (int li = 0; li < 128; ++li) {
        int l = l0 + li;
        float wv = base[l * 32 + k];
#pragma unroll
        for (int r = 0; r < 4; ++r) acc[r] = fmaf(wv, T[r][l], acc[r]);
    }
#pragma unroll
    for (int r = 0; r < 4; ++r) S2[w][r][lane] = acc[r];
    __syncthreads();

    int r = w;
    float tot = S2[0][r][lane] + S2[1][r][lane] + S2[2][r][lane] + S2[3][r][lane];
    float sq = tot * tot;
#pragma unroll
    for (int off = 1; off < 32; off <<= 1) sq += __shfl_xor(sq, off);
    float nrm = sqrtf(sq + EPSF);
    float o = tot / nrm;
    int row = r0 + r;
    if (lane < 32) vxn[(size_t)row * 32 + lane] = o;
    else           vhn[(size_t)row * 32 + (lane - 32)] = o;
}

// ---------------- K3: pearson + top-32 (radix ballot select) + sparse softmax
//                     + gated mix + attn mean.  Block = one n; wave = one b.
__global__ __launch_bounds__(256) void k_attn(
    const float* __restrict__ vxn, const float* __restrict__ vhn,
    const float* __restrict__ embedBuf, const float* __restrict__ sumEmbed,
    float* __restrict__ outO, float* __restrict__ outA) {
    __shared__ float plds[4][512];
    __shared__ int   sIdx[4][32];
    __shared__ float sVal[4][32];
    int tid = threadIdx.x;
    int b = tid >> 6, lane = tid & 63;
    int n = blockIdx.x;

    const float* vxp = vxn + ((size_t)(b * 512 + n)) * 32;
    float xk[32];
#pragma unroll
    for (int k2 = 0; k2 < 32; ++k2) xk[k2] = vxp[k2];   // wave-uniform

    float p[8];
    unsigned int kk[8];
#pragma unroll
    for (int jj = 0; jj < 8; ++jj) {
        int m = jj * 64 + lane;
        const float4* vp = (const float4*)(vhn + ((size_t)(b * 512 + m)) * 32);
        float acc = 0.f;
#pragma unroll
        for (int c = 0; c < 8; ++c) {
            float4 v4 = vp[c];
            acc = fmaf(xk[c * 4 + 0], v4.x, acc);
            acc = fmaf(xk[c * 4 + 1], v4.y, acc);
            acc = fmaf(xk[c * 4 + 2], v4.z, acc);
            acc = fmaf(xk[c * 4 + 3], v4.w, acc);
        }
        p[jj] = acc;
        plds[b][m] = acc;
        unsigned int u = __float_as_uint(acc);
        kk[jj] = (u & 0x80000000u) ? ~u : (u | 0x80000000u);  // order-preserving key
    }
    __syncthreads();

    // attn = mean over b
#pragma unroll
    for (int c = 0; c < 2; ++c) {
        int m = tid + c * 256;
        outA[(size_t)n * 512 + m] =
            0.25f * (plds[0][m] + plds[1][m] + plds[2][m] + plds[3][m]);
    }

    // row max (for softmax shift): one butterfly, overlaps with radix search
    float lv = p[0];
#pragma unroll
    for (int j = 1; j < 8; ++j) lv = fmaxf(lv, p[j]);
#pragma unroll
    for (int off = 1; off < 64; off <<= 1) lv = fmaxf(lv, __shfl_xor(lv, off));
    float M = fmaxf(lv, 0.f);

    // radix binary search: T32 = 32nd-largest key
    unsigned int prefix = 0u;
#pragma unroll
    for (int bit = 31; bit >= 0; --bit) {
        unsigned int cand = prefix | (1u << bit);
        int cnt = 0;
#pragma unroll
        for (int j = 0; j < 8; ++j)
            cnt += __popcll(__ballot(kk[j] >= cand));
        if (cnt >= KK) prefix = cand;
    }

    // selection: strict-greater, plus ties at T32 filled in ascending m order
    unsigned long long eq[8];
    int cgt = 0;
#pragma unroll
    for (int j = 0; j < 8; ++j) {
        cgt += __popcll(__ballot(kk[j] > prefix));
        eq[j] = __ballot(kk[j] == prefix);
    }
    int need = KK - cgt;
    unsigned long long lmask = lane ? (~0ull >> (64 - lane)) : 0ull;
    bool sel[8];
    int myCnt = 0, takenBefore = 0;
#pragma unroll
    for (int j = 0; j < 8; ++j) {
        bool s = (kk[j] > prefix);
        if (!s && kk[j] == prefix) {
            int rank = takenBefore + __popcll(eq[j] & lmask);
            s = (rank < need);
        }
        takenBefore += __popcll(eq[j]);
        sel[j] = s;
        myCnt += s ? 1 : 0;
    }

    // exclusive prefix-sum of per-lane counts -> compaction slots
    int inc = myCnt;
#pragma unroll
    for (int d2 = 1; d2 < 64; d2 <<= 1) {
        int t = __shfl_up(inc, d2);
        if (lane >= d2) inc += t;
    }
    int slot = inc - myCnt;
#pragma unroll
    for (int j = 0; j < 8; ++j) {
        if (sel[j]) {
            sIdx[b][slot] = j * 64 + lane;
            sVal[b][slot] = p[j];
            slot++;
        }
    }
    __syncthreads();

    // sparse softmax + gather-mix (independent, pipelined loads)
    float enM = __expf(-M);
    float expsum = (float)(NN - KK) * enM;   // 480 zeros contribute e^{-M}
    float oacc = 0.f;
    const float* eb = embedBuf + (size_t)b * 512 * 64;
#pragma unroll 8
    for (int i = 0; i < KK; ++i) {
        int mi = sIdx[b][i];
        float wv = __expf(sVal[b][i] - M);
        expsum += wv;
        oacc = fmaf(wv - enM, eb[(size_t)mi * 64 + lane], oacc);
    }
    oacc = fmaf(enM, sumEmbed[b * 64 + lane], oacc);
    oacc /= expsum;
    outO[((size_t)(b * 512 + n)) * 64 + lane] = oacc;
}

extern "C" void kernel_launch(void* const* d_in, const int* in_sizes, int n_in,
                              void* d_out, int out_size, void* d_ws, size_t ws_size,
                              hipStream_t stream) {
    const float* x      = (const float*)d_in[0];
    const float* target = (const float*)d_in[1];
    const float* cw     = (const float*)d_in[2];
    const float* pw     = (const float*)d_in[3];
    const float* pb     = (const float*)d_in[4];
    const float* W0     = (const float*)d_in[5];
    const float* U0     = (const float*)d_in[6];

    float* out  = (float*)d_out;                 // (4,512,64)
    float* attn = out + 4 * 512 * 64;            // (512,512)

    float* ws       = (float*)d_ws;
    float* embedBuf = ws;                        // 131072
    float* sumEmbed = ws + 131072;               // 256
    float* vxn      = ws + 131328;               // 65536
    float* vhn      = ws + 196864;               // 65536
    float* Ct       = ws + 262400;               // 12800

    k_transpose_cw<<<50, 256, 0, stream>>>(cw, Ct);
    k_embed<<<512, 256, 0, stream>>>(x, pw, pb, Ct, embedBuf);
    k_sumembed<<<4, 256, 0, stream>>>(embedBuf, sumEmbed);
    k_corr<<<512, 256, 0, stream>>>(target, W0, U0, vxn, vhn);
    k_attn<<<512, 256, 0, stream>>>(vxn, vhn, embedBuf, sumEmbed, out, attn);
}

// Round 4
// 161.754 us; speedup vs baseline: 1.1226x; 1.1205x over previous
//
#include <hip/hip_runtime.h>
#include <math.h>

#define BB 4
#define NN 512
#define LL 512
#define HH 8
#define DD 64
#define EE 25
#define KK 32
#define LOUT 416
#define EPSF 1e-6f

// ws layout (floats):
//  [0,        131072)  embedBuf  (2048 x 64)
//  [131072,   131328)  sumEmbed  (4 x 64)
//  [131328,   196864)  vxn       (2048 x 32)   row-major (b,n,k)
//  [196864,   262400)  vhnT      (4 x 32 x 512) transposed (b,k,n)
//  [262400,   275200)  Ct        (200 x 64)    conv_w transposed

// ---------------- K0: transpose conv_w (D,H,E) -> ((h,e), d)
__global__ void k_transpose_cw(const float* __restrict__ cw, float* __restrict__ Ct) {
    int i = blockIdx.x * 256 + threadIdx.x;
    if (i < DD * HH * EE) {
        int d = i / (HH * EE);
        int he = i % (HH * EE);
        Ct[he * DD + d] = cw[i];
    }
}

// ---------------- K1: fused dilated-conv + proj + GELU -> embed (2048 x 64)
// Block = one bn row, 4 waves; wave w covers j in [16w, 16w+16) (l = q + 8j).
__global__ __launch_bounds__(256, 4) void k_embed(
    const float* __restrict__ x, const float* __restrict__ pw,
    const float* __restrict__ pb, const float* __restrict__ Ct,
    float* __restrict__ embedBuf) {
    __shared__ float P[608];          // P[96+t] = pw[t], zero outside [0,416)
    __shared__ float Sred[4][200];    // per-wave q-reduced S[h][e]
    __shared__ float Stot[200];
    __shared__ float opart[4][64];
    int tid = threadIdx.x;
    for (int i = tid; i < 608; i += 256) {
        int t = i - 96;
        P[i] = (t >= 0 && t < LOUT) ? pw[t] : 0.f;
    }
    __syncthreads();

    int w = tid >> 6, lane = tid & 63;
    int bn = blockIdx.x;
    const float* xp = x + (size_t)bn * (LL * HH);
    int q = lane >> 3;
    int jb = 16 * w;

    float W[25];
#pragma unroll
    for (int k = 0; k < 25; ++k) W[k] = P[q + 8 * jb + 4 * k];
    float S[25];
#pragma unroll
    for (int e = 0; e < 25; ++e) S[e] = 0.f;

#pragma unroll
    for (int jl = 0; jl < 16; ++jl) {
        int j = jb + jl;
        float v = xp[64 * j + lane];          // x[l = q+8j, h=lane&7]
#pragma unroll
        for (int k = 0; k < 25; ++k)
            S[24 - k] = fmaf(v, W[k], S[24 - k]);
        if (jl < 15) {                        // slide window by 8 (= 2 slots)
#pragma unroll
            for (int k = 0; k < 23; ++k) W[k] = W[k + 2];
            int l = q + 8 * j;
            W[23] = P[l + 100];
            W[24] = P[l + 104];
        }
    }
    // reduce over q (lanes 8 apart share h)
#pragma unroll
    for (int e = 0; e < 25; ++e) {
        S[e] += __shfl_xor(S[e], 8);
        S[e] += __shfl_xor(S[e], 16);
        S[e] += __shfl_xor(S[e], 32);
    }
    if (lane < 8) {
#pragma unroll
        for (int e = 0; e < 25; ++e) Sred[w][lane * 25 + e] = S[e];
    }
    __syncthreads();
    if (tid < 200)
        Stot[tid] = Sred[0][tid] + Sred[1][tid] + Sred[2][tid] + Sred[3][tid];
    __syncthreads();

    // stage 3: wave w covers i in [50w, 50w+50)
    float acc = 0.f;
#pragma unroll 10
    for (int ii = 0; ii < 50; ++ii) {
        int i = 50 * w + ii;
        acc = fmaf(Ct[i * 64 + lane], Stot[i], acc);
    }
    opart[w][lane] = acc;
    __syncthreads();
    if (w == 0) {
        float a = opart[0][lane] + opart[1][lane] + opart[2][lane] + opart[3][lane]
                + pb[0];
        float g = 0.5f * a * (1.f + erff(a * 0.70710678118654752f));
        embedBuf[(size_t)bn * 64 + lane] = g;
    }
}

// ---------------- K1b: sumEmbed[b][d] = sum_n embed[b,n,d]
__global__ __launch_bounds__(256) void k_sumembed(
    const float* __restrict__ embedBuf, float* __restrict__ sumEmbed) {
    int b = blockIdx.x, tid = threadIdx.x;
    int d = tid & 63, c = tid >> 6;
    float s = 0.f;
    for (int r = c; r < 512; r += 4)
        s += embedBuf[((size_t)b * 512 + r) * 64 + d];
    __shared__ float red[4][64];
    red[c][d] = s;
    __syncthreads();
    if (c == 0)
        sumEmbed[b * 64 + d] = red[0][d] + red[1][d] + red[2][d] + red[3][d];
}

// ---------------- K2: centered target rows -> normalized vx (row-major), vhT
// Block = 2 rows; wave w = l-chunk [128w,128w+128); lane<32 -> W0, else U0.
__global__ __launch_bounds__(256, 4) void k_corr(
    const float* __restrict__ target, const float* __restrict__ W0,
    const float* __restrict__ U0, float* __restrict__ vxn, float* __restrict__ vhnT) {
    __shared__ float T[2][512];
    __shared__ float mus[2];
    __shared__ float S2[4][2][64];
    int tid = threadIdx.x;
    int w = tid >> 6, lane = tid & 63;
    int r0 = blockIdx.x * 2;

    const float4* tp = (const float4*)(target + (size_t)r0 * 512);
    ((float4*)&T[0][0])[tid] = tp[tid];
    __syncthreads();

    if (w < 2) {
        float s = 0.f;
#pragma unroll
        for (int c = 0; c < 8; ++c) s += T[w][lane + 64 * c];
#pragma unroll
        for (int off = 1; off < 64; off <<= 1) s += __shfl_xor(s, off);
        if (lane == 0) mus[w] = s * (1.f / 512.f);
    }
    __syncthreads();
#pragma unroll
    for (int c = 0; c < 4; ++c) {
        int i = tid + c * 256;
        T[i >> 9][i & 511] -= mus[i >> 9];
    }
    __syncthreads();

    const float* base = (lane < 32) ? W0 : U0;
    int k = lane & 31;
    float acc0 = 0.f, acc1 = 0.f;
    int l0 = w * 128;
#pragma unroll 4
    for (int li = 0; li < 128; ++li) {
        int l = l0 + li;
        float wv = base[l * 32 + k];
        acc0 = fmaf(wv, T[0][l], acc0);
        acc1 = fmaf(wv, T[1][l], acc1);
    }
    S2[w][0][lane] = acc0;
    S2[w][1][lane] = acc1;
    __syncthreads();

    if (w < 2) {
        int r = w;
        float tot = S2[0][r][lane] + S2[1][r][lane] + S2[2][r][lane] + S2[3][r][lane];
        float sq = tot * tot;
#pragma unroll
        for (int off = 1; off < 32; off <<= 1) sq += __shfl_xor(sq, off);
        float o = tot / sqrtf(sq + EPSF);
        int row = r0 + r, b = row >> 9, n = row & 511;
        if (lane < 32) vxn[(size_t)row * 32 + lane] = o;
        else           vhnT[(size_t)b * (32 * 512) + (lane - 32) * 512 + n] = o;
    }
}

// ---------------- K3: pearson + top-32 (2-stage radix, 41-bit keys) + sparse
// softmax + gated mix + attn (atomic mean).  Block = one (b,n), 4 waves.
__device__ __forceinline__ unsigned long long mkkey(float v, int m) {
    unsigned u = __float_as_uint(v);
    u = (u & 0x80000000u) ? ~u : (u | 0x80000000u);   // order-preserving
    return ((unsigned long long)u << 9) | (unsigned)(511 - m);  // tie -> low m
}

__global__ __launch_bounds__(256, 4) void k_attn(
    const float* __restrict__ vxn, const float* __restrict__ vhnT,
    const float* __restrict__ embedBuf, const float* __restrict__ sumEmbed,
    float* __restrict__ outO, float* __restrict__ outA) {
    __shared__ float candVal[128];
    __shared__ int   candIdx[128];
    __shared__ float sSelVal[32];
    __shared__ int   sSelIdx[32];
    __shared__ float opart[4][64];
    __shared__ float esum[4];
    __shared__ float sM[1];
    int tid = threadIdx.x, w = tid >> 6, lane = tid & 63;
    int bid = blockIdx.x;
    int b = bid >> 9, n = bid & 511;

    const float* vxp = vxn + ((size_t)(b * 512 + n)) * 32;
    float xk[32];
#pragma unroll
    for (int k = 0; k < 32; ++k) xk[k] = vxp[k];      // wave-uniform

    int m0 = w * 128 + lane;
    const float* vt = vhnT + (size_t)b * (32 * 512);
    float a0 = 0.f, a1 = 0.f;
#pragma unroll
    for (int k = 0; k < 32; ++k) {
        float v0 = vt[k * 512 + m0];
        float v1 = vt[k * 512 + m0 + 64];
        a0 = fmaf(xk[k], v0, a0);
        a1 = fmaf(xk[k], v1, a1);
    }
    atomicAdd(&outA[(size_t)n * 512 + m0], 0.25f * a0);
    atomicAdd(&outA[(size_t)n * 512 + m0 + 64], 0.25f * a1);

    // ---- stage A: per-wave top-32 of its 128 values (keys all distinct)
    unsigned long long k0 = mkkey(a0, m0), k1 = mkkey(a1, m0 + 64);
    unsigned long long prefix = 0ull;
    for (int bit = 40; bit >= 0; --bit) {
        unsigned long long cand = prefix | (1ull << bit);
        int cnt = __popcll(__ballot(k0 >= cand)) + __popcll(__ballot(k1 >= cand));
        if (cnt >= KK) prefix = cand;
    }
    bool s0 = (k0 >= prefix), s1 = (k1 >= prefix);
    unsigned long long b0 = __ballot(s0), b1 = __ballot(s1);
    unsigned long long lm = lane ? (~0ull >> (64 - lane)) : 0ull;
    int basec = w * 32;
    if (s0) { int sl = basec + __popcll(b0 & lm); candVal[sl] = a0; candIdx[sl] = m0; }
    if (s1) { int sl = basec + __popcll(b0) + __popcll(b1 & lm);
              candVal[sl] = a1; candIdx[sl] = m0 + 64; }
    __syncthreads();

    // ---- stage B: wave 0 merges 128 candidates -> exact top-32
    if (w == 0) {
        float v0 = candVal[lane],  v1 = candVal[64 + lane];
        int   i0 = candIdx[lane],  i1 = candIdx[64 + lane];
        unsigned long long c0 = mkkey(v0, i0), c1 = mkkey(v1, i1);
        unsigned long long pfx = 0ull;
        for (int bit = 40; bit >= 0; --bit) {
            unsigned long long cand = pfx | (1ull << bit);
            int cnt = __popcll(__ballot(c0 >= cand)) + __popcll(__ballot(c1 >= cand));
            if (cnt >= KK) pfx = cand;
        }
        bool t0 = (c0 >= pfx), t1 = (c1 >= pfx);
        unsigned long long d0 = __ballot(t0), d1 = __ballot(t1);
        if (t0) { int sl = __popcll(d0 & lm); sSelVal[sl] = v0; sSelIdx[sl] = i0; }
        if (t1) { int sl = __popcll(d0) + __popcll(d1 & lm);
                  sSelVal[sl] = v1; sSelIdx[sl] = i1; }
        float mx = fmaxf(v0, v1);
#pragma unroll
        for (int off = 1; off < 64; off <<= 1) mx = fmaxf(mx, __shfl_xor(mx, off));
        if (lane == 0) sM[0] = fmaxf(mx, 0.f);
    }
    __syncthreads();

    // ---- sparse softmax + gather mix: wave w handles 8 selected entries
    float M = sM[0];
    float enM = __expf(-M);
    float oacc = 0.f, es = 0.f;
    const float* eb = embedBuf + (size_t)b * 512 * 64;
#pragma unroll
    for (int i = 0; i < 8; ++i) {
        int idx = sSelIdx[w * 8 + i];
        float wv = __expf(sSelVal[w * 8 + i] - M);
        es += wv;
        oacc = fmaf(wv - enM, eb[(size_t)idx * 64 + lane], oacc);
    }
    opart[w][lane] = oacc;
    if (lane == 0) esum[w] = es;
    __syncthreads();
    if (w == 0) {
        float o = opart[0][lane] + opart[1][lane] + opart[2][lane] + opart[3][lane];
        float E = esum[0] + esum[1] + esum[2] + esum[3] + (float)(NN - KK) * enM;
        o = fmaf(enM, sumEmbed[b * 64 + lane], o);
        outO[((size_t)(b * 512 + n)) * 64 + lane] = o / E;
    }
}

extern "C" void kernel_launch(void* const* d_in, const int* in_sizes, int n_in,
                              void* d_out, int out_size, void* d_ws, size_t ws_size,
                              hipStream_t stream) {
    const float* x      = (const float*)d_in[0];
    const float* target = (const float*)d_in[1];
    const float* cw     = (const float*)d_in[2];
    const float* pw     = (const float*)d_in[3];
    const float* pb     = (const float*)d_in[4];
    const float* W0     = (const float*)d_in[5];
    const float* U0     = (const float*)d_in[6];

    float* out  = (float*)d_out;                 // (4,512,64)
    float* attn = out + 4 * 512 * 64;            // (512,512)

    float* ws       = (float*)d_ws;
    float* embedBuf = ws;                        // 131072
    float* sumEmbed = ws + 131072;               // 256
    float* vxn      = ws + 131328;               // 65536
    float* vhnT     = ws + 196864;               // 65536
    float* Ct       = ws + 262400;               // 12800

    hipMemsetAsync(attn, 0, 512 * 512 * sizeof(float), stream);
    k_transpose_cw<<<50, 256, 0, stream>>>(cw, Ct);
    k_embed<<<2048, 256, 0, stream>>>(x, pw, pb, Ct, embedBuf);
    k_sumembed<<<4, 256, 0, stream>>>(embedBuf, sumEmbed);
    k_corr<<<1024, 256, 0, stream>>>(target, W0, U0, vxn, vhnT);
    k_attn<<<2048, 256, 0, stream>>>(vxn, vhnT, embedBuf, sumEmbed, out, attn);
}

// Round 7
// 135.418 us; speedup vs baseline: 1.3409x; 1.1945x over previous
//
#include <hip/hip_runtime.h>
#include <math.h>

#define BB 4
#define NN 512
#define LL 512
#define HH 8
#define DD 64
#define EE 25
#define KK 32
#define LOUT 416
#define EPSF 1e-6f

// ws layout (floats):
//  [0,        131072)   embedBuf  (2048 x 64)
//  [131072,   131328)   sumEmbed  (4 x 64)
//  [131328,   196864)   vxn       (2048 x 32)    row-major (b,n,k)
//  [196864,   262400)   vhnT      (4 x 32 x 512) transposed (b,k,n)
//  [262400,   275200)   Ct        (200 x 64)     conv_w transposed
//  [275200,  1323776)   pbuf      (4 x 512 x 512) pearson (b,n,m)

// ---------------- K0: transpose conv_w (D,H,E) -> ((h,e), d)
__global__ void k_transpose_cw(const float* __restrict__ cw, float* __restrict__ Ct) {
    int i = blockIdx.x * 256 + threadIdx.x;
    if (i < DD * HH * EE) {
        int d = i / (HH * EE);
        int he = i % (HH * EE);
        Ct[he * DD + d] = cw[i];
    }
}

// ---------------- fused K1(embed, 2048 blocks) + K2(corr, 1024 blocks)
// block bid: bid%3==2 -> corr pair bid/3 ; else embed row (bid/3)*2 + bid%3
__global__ __launch_bounds__(256, 4) void k_fused(
    const float* __restrict__ x, const float* __restrict__ pw,
    const float* __restrict__ pb, const float* __restrict__ Ct,
    float* __restrict__ embedBuf,
    const float* __restrict__ target, const float* __restrict__ W0,
    const float* __restrict__ U0, float* __restrict__ vxn,
    float* __restrict__ vhnT) {
    // embed smem
    __shared__ float P[608];
    __shared__ float Sred[4][200];
    __shared__ float Stot[200];
    __shared__ float opart[4][64];
    // corr smem
    __shared__ float T[2][512];
    __shared__ float mus[2];
    __shared__ float S2[4][2][64];

    int tid = threadIdx.x;
    int w = tid >> 6, lane = tid & 63;
    int bid = blockIdx.x;
    int sel = bid % 3;

    if (sel != 2) {
        // ================= embed body =================
        int bn = (bid / 3) * 2 + sel;
        for (int i = tid; i < 608; i += 256) {
            int t = i - 96;
            P[i] = (t >= 0 && t < LOUT) ? pw[t] : 0.f;
        }
        __syncthreads();

        const float* xp = x + (size_t)bn * (LL * HH);
        int q = lane >> 3;
        int jb = 16 * w;

        float W[25];
#pragma unroll
        for (int k = 0; k < 25; ++k) W[k] = P[q + 8 * jb + 4 * k];
        float S[25];
#pragma unroll
        for (int e = 0; e < 25; ++e) S[e] = 0.f;

#pragma unroll
        for (int jl = 0; jl < 16; ++jl) {
            int j = jb + jl;
            float v = xp[64 * j + lane];          // x[l = q+8j, h=lane&7]
#pragma unroll
            for (int k = 0; k < 25; ++k)
                S[24 - k] = fmaf(v, W[k], S[24 - k]);
            if (jl < 15) {                        // slide window by 8 (= 2 slots)
#pragma unroll
                for (int k = 0; k < 23; ++k) W[k] = W[k + 2];
                int l = q + 8 * j;
                W[23] = P[l + 100];
                W[24] = P[l + 104];
            }
        }
#pragma unroll
        for (int e = 0; e < 25; ++e) {
            S[e] += __shfl_xor(S[e], 8);
            S[e] += __shfl_xor(S[e], 16);
            S[e] += __shfl_xor(S[e], 32);
        }
        if (lane < 8) {
#pragma unroll
            for (int e = 0; e < 25; ++e) Sred[w][lane * 25 + e] = S[e];
        }
        __syncthreads();
        if (tid < 200)
            Stot[tid] = Sred[0][tid] + Sred[1][tid] + Sred[2][tid] + Sred[3][tid];
        __syncthreads();

        float acc = 0.f;
#pragma unroll 10
        for (int ii = 0; ii < 50; ++ii) {
            int i = 50 * w + ii;
            acc = fmaf(Ct[i * 64 + lane], Stot[i], acc);
        }
        opart[w][lane] = acc;
        __syncthreads();
        if (w == 0) {
            float a = opart[0][lane] + opart[1][lane] + opart[2][lane]
                    + opart[3][lane] + pb[0];
            float g = 0.5f * a * (1.f + erff(a * 0.70710678118654752f));
            embedBuf[(size_t)bn * 64 + lane] = g;
        }
    } else {
        // ================= corr body =================
        int r0 = (bid / 3) * 2;
        const float4* tp = (const float4*)(target + (size_t)r0 * 512);
        ((float4*)&T[0][0])[tid] = tp[tid];
        __syncthreads();

        if (w < 2) {
            float s = 0.f;
#pragma unroll
            for (int c = 0; c < 8; ++c) s += T[w][lane + 64 * c];
#pragma unroll
            for (int off = 1; off < 64; off <<= 1) s += __shfl_xor(s, off);
            if (lane == 0) mus[w] = s * (1.f / 512.f);
        }
        __syncthreads();
#pragma unroll
        for (int c = 0; c < 4; ++c) {
            int i = tid + c * 256;
            T[i >> 9][i & 511] -= mus[i >> 9];
        }
        __syncthreads();

        const float* base = (lane < 32) ? W0 : U0;
        int k = lane & 31;
        float acc0 = 0.f, acc1 = 0.f;
        int l0 = w * 128;
#pragma unroll 4
        for (int li = 0; li < 128; ++li) {
            int l = l0 + li;
            float wv = base[l * 32 + k];
            acc0 = fmaf(wv, T[0][l], acc0);
            acc1 = fmaf(wv, T[1][l], acc1);
        }
        S2[w][0][lane] = acc0;
        S2[w][1][lane] = acc1;
        __syncthreads();

        if (w < 2) {
            int r = w;
            float tot = S2[0][r][lane] + S2[1][r][lane] + S2[2][r][lane]
                      + S2[3][r][lane];
            float sq = tot * tot;
#pragma unroll
            for (int off = 1; off < 32; off <<= 1) sq += __shfl_xor(sq, off);
            float o = tot / sqrtf(sq + EPSF);
            int row = r0 + r, b = row >> 9, n = row & 511;
            if (lane < 32) vxn[(size_t)row * 32 + lane] = o;
            else           vhnT[(size_t)b * (32 * 512) + (lane - 32) * 512 + n] = o;
        }
    }
}

// ---------------- K1b: sumEmbed[b][d] = sum_n embed[b,n,d]
__global__ __launch_bounds__(1024) void k_sumembed(
    const float* __restrict__ embedBuf, float* __restrict__ sumEmbed) {
    int b = blockIdx.x, tid = threadIdx.x;
    int d = tid & 63, c = tid >> 6;        // c in [0,16)
    float s = 0.f;
    for (int r = c; r < 512; r += 16)
        s += embedBuf[((size_t)b * 512 + r) * 64 + d];
    __shared__ float red[16][64];
    red[c][d] = s;
    __syncthreads();
    if (c == 0) {
        float t = 0.f;
#pragma unroll
        for (int j = 0; j < 16; ++j) t += red[j][d];
        sumEmbed[b * 64 + d] = t;
    }
}

// ---------------- K3: pearson + top-32 (2-stage radix, 41-bit keys) + sparse
// softmax + gated mix; stores P for the mean kernel.  Block = one (b,n).
__device__ __forceinline__ unsigned long long mkkey(float v, int m) {
    unsigned u = __float_as_uint(v);
    u = (u & 0x80000000u) ? ~u : (u | 0x80000000u);   // order-preserving
    return ((unsigned long long)u << 9) | (unsigned)(511 - m);  // tie -> low m
}

__global__ __launch_bounds__(256, 8) void k_attn(
    const float* __restrict__ vxn, const float* __restrict__ vhnT,
    const float* __restrict__ embedBuf, const float* __restrict__ sumEmbed,
    float* __restrict__ outO, float* __restrict__ pbuf) {
    __shared__ float candVal[128];
    __shared__ int   candIdx[128];
    __shared__ float sSelVal[32];
    __shared__ int   sSelIdx[32];
    __shared__ float opart[4][64];
    __shared__ float esum[4];
    __shared__ float sM[1];
    int tid = threadIdx.x, w = tid >> 6, lane = tid & 63;
    int bid = blockIdx.x;
    int b = bid >> 9, n = bid & 511;

    const float* vxp = vxn + ((size_t)(b * 512 + n)) * 32;
    float xk[32];
#pragma unroll
    for (int k = 0; k < 32; ++k)           // force into SGPRs (wave-uniform)
        xk[k] = __uint_as_float(__builtin_amdgcn_readfirstlane(
                    __float_as_uint(vxp[k])));

    int m0 = w * 128 + lane;
    const float* vt = vhnT + (size_t)b * (32 * 512);
    float a0 = 0.f, a1 = 0.f;
#pragma unroll
    for (int k = 0; k < 32; ++k) {
        float v0 = vt[k * 512 + m0];
        float v1 = vt[k * 512 + m0 + 64];
        a0 = fmaf(xk[k], v0, a0);
        a1 = fmaf(xk[k], v1, a1);
    }
    float* pr = pbuf + ((size_t)(b * 512 + n)) * 512;
    pr[m0] = a0;
    pr[m0 + 64] = a1;

    // ---- stage A: per-wave top-32 of its 128 values (keys all distinct)
    unsigned long long k0 = mkkey(a0, m0), k1 = mkkey(a1, m0 + 64);
    unsigned long long prefix = 0ull;
    for (int bit = 40; bit >= 0; --bit) {
        unsigned long long cand = prefix | (1ull << bit);
        int cnt = __popcll(__ballot(k0 >= cand)) + __popcll(__ballot(k1 >= cand));
        if (cnt >= KK) prefix = cand;
    }
    bool s0 = (k0 >= prefix), s1 = (k1 >= prefix);
    unsigned long long b0 = __ballot(s0), b1 = __ballot(s1);
    unsigned long long lm = lane ? (~0ull >> (64 - lane)) : 0ull;
    int basec = w * 32;
    if (s0) { int sl = basec + __popcll(b0 & lm); candVal[sl] = a0; candIdx[sl] = m0; }
    if (s1) { int sl = basec + __popcll(b0) + __popcll(b1 & lm);
              candVal[sl] = a1; candIdx[sl] = m0 + 64; }
    __syncthreads();

    // ---- stage B: wave 0 merges 128 candidates -> exact top-32
    if (w == 0) {
        float v0 = candVal[lane],  v1 = candVal[64 + lane];
        int   i0 = candIdx[lane],  i1 = candIdx[64 + lane];
        unsigned long long c0 = mkkey(v0, i0), c1 = mkkey(v1, i1);
        unsigned long long pfx = 0ull;
        for (int bit = 40; bit >= 0; --bit) {
            unsigned long long cand = pfx | (1ull << bit);
            int cnt = __popcll(__ballot(c0 >= cand)) + __popcll(__ballot(c1 >= cand));
            if (cnt >= KK) pfx = cand;
        }
        bool t0 = (c0 >= pfx), t1 = (c1 >= pfx);
        unsigned long long d0 = __ballot(t0), d1 = __ballot(t1);
        if (t0) { int sl = __popcll(d0 & lm); sSelVal[sl] = v0; sSelIdx[sl] = i0; }
        if (t1) { int sl = __popcll(d0) + __popcll(d1 & lm);
                  sSelVal[sl] = v1; sSelIdx[sl] = i1; }
        float mx = fmaxf(v0, v1);
#pragma unroll
        for (int off = 1; off < 64; off <<= 1) mx = fmaxf(mx, __shfl_xor(mx, off));
        if (lane == 0) sM[0] = fmaxf(mx, 0.f);
    }
    __syncthreads();

    // ---- sparse softmax + gather mix: wave w handles 8 selected entries
    float M = sM[0];
    float enM = __expf(-M);
    float oacc = 0.f, es = 0.f;
    const float* eb = embedBuf + (size_t)b * 512 * 64;
#pragma unroll
    for (int i = 0; i < 8; ++i) {
        int idx = sSelIdx[w * 8 + i];
        float wv = __expf(sSelVal[w * 8 + i] - M);
        es += wv;
        oacc = fmaf(wv - enM, eb[(size_t)idx * 64 + lane], oacc);
    }
    opart[w][lane] = oacc;
    if (lane == 0) esum[w] = es;
    __syncthreads();
    if (w == 0) {
        float o = opart[0][lane] + opart[1][lane] + opart[2][lane] + opart[3][lane];
        float E = esum[0] + esum[1] + esum[2] + esum[3] + (float)(NN - KK) * enM;
        o = fmaf(enM, sumEmbed[b * 64 + lane], o);
        outO[((size_t)(b * 512 + n)) * 64 + lane] = o / E;
    }
}

// ---------------- K4: attn[n][m] = mean_b pbuf[b][n][m]
__global__ __launch_bounds__(256) void k_mean(
    const float* __restrict__ pbuf, float* __restrict__ outA) {
    int i = blockIdx.x * 256 + threadIdx.x;      // [0, 262144)
    float s = pbuf[i] + pbuf[262144 + i] + pbuf[524288 + i] + pbuf[786432 + i];
    outA[i] = 0.25f * s;
}

extern "C" void kernel_launch(void* const* d_in, const int* in_sizes, int n_in,
                              void* d_out, int out_size, void* d_ws, size_t ws_size,
                              hipStream_t stream) {
    const float* x      = (const float*)d_in[0];
    const float* target = (const float*)d_in[1];
    const float* cw     = (const float*)d_in[2];
    const float* pw     = (const float*)d_in[3];
    const float* pb     = (const float*)d_in[4];
    const float* W0     = (const float*)d_in[5];
    const float* U0     = (const float*)d_in[6];

    float* out  = (float*)d_out;                 // (4,512,64)
    float* attn = out + 4 * 512 * 64;            // (512,512)

    float* ws       = (float*)d_ws;
    float* embedBuf = ws;                        // 131072
    float* sumEmbed = ws + 131072;               // 256
    float* vxn      = ws + 131328;               // 65536
    float* vhnT     = ws + 196864;               // 65536
    float* Ct       = ws + 262400;               // 12800
    float* pbuf     = ws + 275200;               // 1048576

    k_transpose_cw<<<50, 256, 0, stream>>>(cw, Ct);
    k_fused<<<3072, 256, 0, stream>>>(x, pw, pb, Ct, embedBuf,
                                      target, W0, U0, vxn, vhnT);
    k_sumembed<<<4, 1024, 0, stream>>>(embedBuf, sumEmbed);
    k_attn<<<2048, 256, 0, stream>>>(vxn, vhnT, embedBuf, sumEmbed, out, pbuf);
    k_mean<<<1024, 256, 0, stream>>>(pbuf, attn);
}